// Round 2
// baseline (478.086 us; speedup 1.0000x reference)
//
#include <hip/hip_runtime.h>

// TTRFluxLayer R5: phi restructured for multi-block residency.
// k1 phi v3: 512 thr / 64-row tile / LDS 34.8KB union -> 4 blocks/CU (32 waves).
//            Weights NOT staged in LDS: B-fragments loaded per-ks straight from
//            global (w1h/w2h are L2-resident, shared by all blocks). Phases now
//            interleave ACROSS blocks, hiding barrier drains. q/k blocks
//            interleaved for tail balance. SiLU uses v_rcp_f32.
// k0 prep / k0b vt / k2 s / k3 pfx / k4 scan: unchanged.
// ws: w1h 64K | w2h 128K | qp 48M | kp 48M | kpT/Wf 48M | S/Wr 48M | vT 24M

typedef __attribute__((ext_vector_type(8))) _Float16 f16x8;
typedef __attribute__((ext_vector_type(4))) _Float16 f16x4;
typedef __attribute__((ext_vector_type(4))) float f32x4;

#define MFMA16(a, b, c) __builtin_amdgcn_mfma_f32_16x16x32_f16((a), (b), (c), 0, 0, 0)

constexpr int BH   = 24;
constexpr int NSEQ = 4096;
constexpr int DD   = 128;
constexpr int FF   = 256;
constexpr int CHK  = 128;
constexpr int NC   = NSEQ / CHK;     // 32
constexpr int NROWS = BH * NSEQ;     // 98304

// ---------------- k0: weight convert ----------------
__global__ void prep_kernel(const float* __restrict__ w1, const float* __restrict__ w2,
                            _Float16* __restrict__ w1h, _Float16* __restrict__ w2h) {
  int i = blockIdx.x * 256 + threadIdx.x;
  if (i < FF * DD) w1h[i] = (_Float16)w1[i];
  if (i < FF * FF) w2h[i] = (_Float16)w2[i];
}

// ---------------- k0b: v -> vT fp16 [bh][d][s] ----------------
__global__ void vt_kernel(const float* __restrict__ v, _Float16* __restrict__ vT) {
  __shared__ __align__(16) _Float16 lt[128][136];
  int blk = blockIdx.x;
  int c = blk & 31, bh = blk >> 5;
  const float* vc = v + ((size_t)bh * NSEQ + c * CHK) * DD;
  int tid = threadIdx.x;
#pragma unroll
  for (int it = 0; it < 16; ++it) {
    int flat = it * 1024 + tid * 4;  // 128s x 128d
    int s = flat >> 7, d0 = flat & 127;
    float4 xv = *(const float4*)&vc[(size_t)s * DD + d0];
    lt[d0 + 0][s] = (_Float16)xv.x;
    lt[d0 + 1][s] = (_Float16)xv.y;
    lt[d0 + 2][s] = (_Float16)xv.z;
    lt[d0 + 3][s] = (_Float16)xv.w;
  }
  __syncthreads();
#pragma unroll
  for (int it = 0; it < 8; ++it) {
    int flat = it * 256 + tid;  // 128d x 16 s-groups
    int d = flat >> 4, sg = flat & 15;
    *(f16x8*)&vT[((size_t)bh * DD + d) * NSEQ + c * CHK + sg * 8] =
        *(const f16x8*)&lt[d][sg * 8];
  }
}

// ---------------- k1: phi v3 (64-row tile, 512 thr, 4 blocks/CU) ----------------
__global__ __launch_bounds__(512, 8)
void phi_kernel(const float* __restrict__ q, const float* __restrict__ k,
                const float* __restrict__ b1, const float* __restrict__ b2,
                const _Float16* __restrict__ w1h, const _Float16* __restrict__ w2h,
                _Float16* __restrict__ qp, _Float16* __restrict__ kp,
                _Float16* __restrict__ kpT) {
  __shared__ __align__(16) char smem[34816];
  _Float16 (*xs)[136] = (_Float16(*)[136])smem;   // [64][136] phase1 (17.4KB)
  _Float16 (*hs)[264] = (_Float16(*)[264])smem;   // [64][264] phase2 (33.8KB)
  _Float16 (*os)[264] = (_Float16(*)[264])smem;   // [64][264] epilogue (alias)
  _Float16 (*ot)[68]  = (_Float16(*)[68])smem;    // [256][68] epilogue-T (34.8KB)
  int blk = blockIdx.x;
  const float* src;
  _Float16* dst;
  bool isk = (blk & 1);
  int rb = (blk >> 1) * 64;
  if (!isk) { src = q; dst = qp; }
  else      { src = k; dst = kp; }
  int tid = threadIdx.x;
  int lane = tid & 63, wv = tid >> 6, lr = lane & 15, lq = lane >> 4;
  int wm = wv & 1, wn = wv >> 1;  // 2 row-strips(32) x 4 F-strips(64)

  // stage x (64x128 f32->f16)
#pragma unroll
  for (int it = 0; it < 4; ++it) {
    int flat = it * 512 + tid;  // 64 rows x 32 d-groups
    int r = flat >> 5, dg = flat & 31;
    float4 xv = *(const float4*)&src[(size_t)(rb + r) * DD + dg * 4];
    f16x4 hv = {(_Float16)xv.x, (_Float16)xv.y, (_Float16)xv.z, (_Float16)xv.w};
    *(f16x4*)&xs[r][dg * 4] = hv;
  }
  __syncthreads();

  // GEMM1: wave tile 32x64 over K=128; B-frags straight from global (L2)
  f32x4 acc[2][4] = {};
#pragma unroll
  for (int ks = 0; ks < 4; ++ks) {
    f16x8 bv[4];
#pragma unroll
    for (int fn = 0; fn < 4; ++fn)
      bv[fn] = *(const f16x8*)&w1h[(size_t)(wn * 64 + fn * 16 + lr) * DD + ks * 32 + lq * 8];
    f16x8 av[2];
#pragma unroll
    for (int im = 0; im < 2; ++im)
      av[im] = *(const f16x8*)&xs[wm * 32 + im * 16 + lr][ks * 32 + lq * 8];
#pragma unroll
    for (int fn = 0; fn < 4; ++fn)
#pragma unroll
      for (int im = 0; im < 2; ++im) acc[im][fn] = MFMA16(av[im], bv[fn], acc[im][fn]);
  }
  __syncthreads();  // xs dead

  // hs = silu(acc + b1)
#pragma unroll
  for (int im = 0; im < 2; ++im)
#pragma unroll
    for (int fn = 0; fn < 4; ++fn) {
      int f = wn * 64 + fn * 16 + lr;
      float bb = b1[f];
      int r0 = wm * 32 + im * 16 + lq * 4;
#pragma unroll
      for (int r = 0; r < 4; ++r) {
        float xv = acc[im][fn][r] + bb;
        hs[r0 + r][f] = (_Float16)(xv * __builtin_amdgcn_rcpf(1.0f + __expf(-xv)));
      }
    }
  __syncthreads();

  // GEMM2: K=256; B-frags straight from global (L2)
  f32x4 ac2[2][4] = {};
#pragma unroll
  for (int ks = 0; ks < 8; ++ks) {
    f16x8 bv[4];
#pragma unroll
    for (int fn = 0; fn < 4; ++fn)
      bv[fn] = *(const f16x8*)&w2h[(size_t)(wn * 64 + fn * 16 + lr) * FF + ks * 32 + lq * 8];
    f16x8 av[2];
#pragma unroll
    for (int im = 0; im < 2; ++im)
      av[im] = *(const f16x8*)&hs[wm * 32 + im * 16 + lr][ks * 32 + lq * 8];
#pragma unroll
    for (int fn = 0; fn < 4; ++fn)
#pragma unroll
      for (int im = 0; im < 2; ++im) ac2[im][fn] = MFMA16(av[im], bv[fn], ac2[im][fn]);
  }
  __syncthreads();  // hs dead

  // epilogue pass 1: row-major tile -> coalesced qp/kp stores
  int bh = rb >> 12, s0 = rb & 4095;
#pragma unroll
  for (int im = 0; im < 2; ++im)
#pragma unroll
    for (int fn = 0; fn < 4; ++fn) {
      int g = wn * 64 + fn * 16 + lr;
      float bb = b2[g];
      int r0 = wm * 32 + im * 16 + lq * 4;
#pragma unroll
      for (int r = 0; r < 4; ++r)
        os[r0 + r][g] = (_Float16)(ac2[im][fn][r] + bb);
    }
  __syncthreads();
#pragma unroll
  for (int it = 0; it < 4; ++it) {
    int flat = it * 512 + tid;  // 64 rows x 32 col-groups
    int r = flat >> 5, cg = flat & 31;
    *(f16x8*)&dst[(size_t)(rb + r) * FF + cg * 8] = *(const f16x8*)&os[r][cg * 8];
  }

  // epilogue pass 2 (k only): transposed tile -> coalesced kpT stores
  if (isk) {
    __syncthreads();  // os drained
#pragma unroll
    for (int im = 0; im < 2; ++im)
#pragma unroll
      for (int fn = 0; fn < 4; ++fn) {
        int g = wn * 64 + fn * 16 + lr;
        float bb = b2[g];
        int r0 = wm * 32 + im * 16 + lq * 4;
#pragma unroll
        for (int r = 0; r < 4; ++r)
          ot[g][r0 + r] = (_Float16)(ac2[im][fn][r] + bb);
      }
    __syncthreads();
#pragma unroll
    for (int it = 0; it < 4; ++it) {
      int flat = it * 512 + tid;  // 256 f x 8 s-groups
      int f = flat >> 3, sg = flat & 7;
      *(f16x8*)&kpT[((size_t)bh * FF + f) * NSEQ + s0 + sg * 8] = *(const f16x8*)&ot[f][sg * 8];
    }
  }
}

// ---------------- k2: S^T[d][f] per chunk ----------------
__global__ __launch_bounds__(512, 2)
void s_kernel(const _Float16* __restrict__ vT, const _Float16* __restrict__ kpT,
              _Float16* __restrict__ S) {
  __shared__ __align__(16) _Float16 vt[128][136];
  __shared__ __align__(16) _Float16 kt[256][136];
  int blk = blockIdx.x;
  int c = blk & 31, bh = blk >> 5;
  int tid = threadIdx.x;
#pragma unroll
  for (int it = 0; it < 4; ++it) {
    int flat = it * 512 + tid;
    int d = flat >> 4, sg = flat & 15;
    *(f16x8*)&vt[d][sg * 8] = *(const f16x8*)&vT[((size_t)bh * DD + d) * NSEQ + c * CHK + sg * 8];
  }
#pragma unroll
  for (int it = 0; it < 8; ++it) {
    int flat = it * 512 + tid;
    int f = flat >> 4, sg = flat & 15;
    *(f16x8*)&kt[f][sg * 8] = *(const f16x8*)&kpT[((size_t)bh * FF + f) * NSEQ + c * CHK + sg * 8];
  }
  __syncthreads();
  int lane = tid & 63, wv = tid >> 6, lr = lane & 15, lq = lane >> 4;
  int wmd = wv & 1, wnf = wv >> 1;
  f32x4 acc[4][4] = {};
#pragma unroll
  for (int ks = 0; ks < 4; ++ks) {
    f16x8 av[4];
#pragma unroll
    for (int im = 0; im < 4; ++im)
      av[im] = *(const f16x8*)&vt[wmd * 64 + im * 16 + lr][ks * 32 + lq * 8];
#pragma unroll
    for (int fn = 0; fn < 4; ++fn) {
      f16x8 bv = *(const f16x8*)&kt[wnf * 64 + fn * 16 + lr][ks * 32 + lq * 8];
#pragma unroll
      for (int im = 0; im < 4; ++im) acc[im][fn] = MFMA16(av[im], bv, acc[im][fn]);
    }
  }
  _Float16* Sp = S + ((size_t)bh * NC + c) * (size_t)(DD * FF);
#pragma unroll
  for (int im = 0; im < 4; ++im)
#pragma unroll
    for (int fn = 0; fn < 4; ++fn) {
      int f = wnf * 64 + fn * 16 + lr;
#pragma unroll
      for (int r = 0; r < 4; ++r) {
        int d = wmd * 64 + im * 16 + lq * 4 + r;
        Sp[(size_t)d * FF + f] = (_Float16)acc[im][fn][r];
      }
    }
}

// ---------------- k3: prefix->Wf, suffix in-place over S (becomes Wr) ------
__global__ void prefix_kernel(_Float16* S_Wr, _Float16* __restrict__ Wf) {
  size_t idx = (size_t)blockIdx.x * 256 + threadIdx.x;
  int bh = (int)(idx >> 15);
  int df = (int)(idx & 32767);
  size_t base = (size_t)bh * NC * 32768 + df;
  float vals[NC];
#pragma unroll
  for (int c = 0; c < NC; ++c) vals[c] = (float)S_Wr[base + (size_t)c * 32768];
  float run = 0.f;
#pragma unroll
  for (int c = 0; c < NC; ++c) { Wf[base + (size_t)c * 32768] = (_Float16)run; run += vals[c]; }
  run = 0.f;
#pragma unroll
  for (int c = NC - 1; c >= 0; --c) { S_Wr[base + (size_t)c * 32768] = (_Float16)run; run += vals[c]; }
}

// ---------------- k4: fused phase-2 scan (full chunk per block) ----------------
__global__ __launch_bounds__(512, 2)
void scan_kernel(const _Float16* __restrict__ qp, const _Float16* __restrict__ kp,
                 const _Float16* __restrict__ vT, const _Float16* __restrict__ Wf,
                 const _Float16* __restrict__ Wr, float* __restrict__ out) {
  __shared__ __align__(16) _Float16 vt[128][136];
  __shared__ __align__(16) _Float16 P[128][136];
  int blk = blockIdx.x;
  int c = blk & 31, bh = blk >> 5;
  const _Float16* qpc = qp + ((size_t)bh * NSEQ + c * CHK) * FF;
  const _Float16* kpc = kp + ((size_t)bh * NSEQ + c * CHK) * FF;
  int tid = threadIdx.x, lane = tid & 63, wv = tid >> 6, lr = lane & 15, lq = lane >> 4;
  int wm = wv & 3, wn = wv >> 2;  // wm: 4x32 rows; wn: 2x64 (s-half in A, d-half in B)

  // aq: 16 frags (reused by phase A and inter), batched but bounded
  f16x8 aq[2][8];
#pragma unroll
  for (int im = 0; im < 2; ++im)
#pragma unroll
    for (int ks = 0; ks < 8; ++ks)
      aq[im][ks] = *(const f16x8*)&qpc[(size_t)(wm * 32 + im * 16 + lr) * FF + ks * 32 + lq * 8];
  // stage vt (b128, conflict-free)
#pragma unroll
  for (int it = 0; it < 4; ++it) {
    int flat = it * 512 + tid;
    int d = flat >> 4, sg = flat & 15;
    *(f16x8*)&vt[d][sg * 8] = *(const f16x8*)&vT[((size_t)bh * DD + d) * NSEQ + c * CHK + sg * 8];
  }
  // Phase A: P = qp.kp^T with bk double-buffer over j
  f16x8 bk[2][8];
#pragma unroll
  for (int ks = 0; ks < 8; ++ks)
    bk[0][ks] = *(const f16x8*)&kpc[(size_t)(wn * 64 + lr) * FF + ks * 32 + lq * 8];
  f32x4 pacc[2][4] = {};
#pragma unroll
  for (int j = 0; j < 4; ++j) {
    int cur = j & 1;
    if (j < 3)
#pragma unroll
      for (int ks = 0; ks < 8; ++ks)
        bk[cur ^ 1][ks] = *(const f16x8*)&kpc[(size_t)(wn * 64 + (j + 1) * 16 + lr) * FF + ks * 32 + lq * 8];
#pragma unroll
    for (int ks = 0; ks < 8; ++ks)
#pragma unroll
      for (int im = 0; im < 2; ++im)
        pacc[im][j] = MFMA16(aq[im][ks], bk[cur][ks], pacc[im][j]);
  }
#pragma unroll
  for (int im = 0; im < 2; ++im)
#pragma unroll
    for (int j = 0; j < 4; ++j)
#pragma unroll
      for (int r = 0; r < 4; ++r)
        P[wm * 32 + im * 16 + lq * 4 + r][wn * 64 + j * 16 + lr] = (_Float16)pacc[im][j][r];

  // prefetch W frags for jd=0 (before barrier: overlaps P writes)
  const _Float16* Wfc = Wf + ((size_t)bh * NC + c) * (size_t)(DD * FF);
  const _Float16* Wrc = Wr + ((size_t)bh * NC + c) * (size_t)(DD * FF);
  f16x8 bf[8], br[8];
#pragma unroll
  for (int ks = 0; ks < 8; ++ks) {
    int d = wn * 64 + lr;
    bf[ks] = *(const f16x8*)&Wfc[(size_t)d * FF + ks * 32 + lq * 8];
    br[ks] = *(const f16x8*)&Wrc[(size_t)d * FF + ks * 32 + lq * 8];
  }
  __syncthreads();

  // Phase B: inter (q.W) per d-group; W prefetch 1 group ahead; intra interleaved
  f32x4 af[2][4] = {}, ar[2][4] = {};
#pragma unroll
  for (int jd = 0; jd < 4; ++jd) {
#pragma unroll
    for (int ks = 0; ks < 8; ++ks)
#pragma unroll
      for (int im = 0; im < 2; ++im) {
        af[im][jd] = MFMA16(aq[im][ks], bf[ks], af[im][jd]);
        ar[im][jd] = MFMA16(aq[im][ks], br[ks], ar[im][jd]);
      }
    if (jd < 3)
#pragma unroll
      for (int ks = 0; ks < 8; ++ks) {
        int d = wn * 64 + (jd + 1) * 16 + lr;
        bf[ks] = *(const f16x8*)&Wfc[(size_t)d * FF + ks * 32 + lq * 8];
        br[ks] = *(const f16x8*)&Wrc[(size_t)d * FF + ks * 32 + lq * 8];
      }
    // intra k-step ks=jd (LDS-only; covers W prefetch latency)
    {
      int ks = jd;
      f16x8 bv[4];
#pragma unroll
      for (int jd2 = 0; jd2 < 4; ++jd2)
        bv[jd2] = *(const f16x8*)&vt[wn * 64 + jd2 * 16 + lr][ks * 32 + lq * 8];
#pragma unroll
      for (int im = 0; im < 2; ++im) {
        int irow = wm * 32 + im * 16 + lr;
        f16x8 p = *(const f16x8*)&P[irow][ks * 32 + lq * 8];
        f16x8 pf = p, pr = p;
#pragma unroll
        for (int jj = 0; jj < 8; ++jj) {
          int s = ks * 32 + lq * 8 + jj;
          pf[jj] = (s <= irow) ? p[jj] : (_Float16)0.0f;
          pr[jj] = (s >= irow) ? p[jj] : (_Float16)0.0f;
        }
#pragma unroll
        for (int jd2 = 0; jd2 < 4; ++jd2) {
          af[im][jd2] = MFMA16(pf, bv[jd2], af[im][jd2]);
          ar[im][jd2] = MFMA16(pr, bv[jd2], ar[im][jd2]);
        }
      }
    }
  }

  // epilogue
  float* oc = out + ((size_t)bh * NSEQ + c * CHK) * DD;
#pragma unroll
  for (int im = 0; im < 2; ++im)
#pragma unroll
    for (int jd = 0; jd < 4; ++jd) {
      int d = wn * 64 + jd * 16 + lr;
#pragma unroll
      for (int r = 0; r < 4; ++r) {
        int il = wm * 32 + im * 16 + lq * 4 + r;
        int gi = c * CHK + il;
        oc[(size_t)il * DD + d] = af[im][jd][r] / (float)(gi + 1) + ar[im][jd][r] / (float)(NSEQ - gi);
      }
    }
}

// ---------------- launcher ----------------
extern "C" void kernel_launch(void* const* d_in, const int* in_sizes, int n_in,
                              void* d_out, int out_size, void* d_ws, size_t ws_size,
                              hipStream_t stream) {
  const float* q  = (const float*)d_in[0];
  const float* k  = (const float*)d_in[1];
  const float* v  = (const float*)d_in[2];
  const float* w1 = (const float*)d_in[3];
  const float* b1 = (const float*)d_in[4];
  const float* w2 = (const float*)d_in[5];
  const float* b2 = (const float*)d_in[6];
  float* out = (float*)d_out;

  char* ws = (char*)d_ws;
  const size_t SZ = 50331648ull;  // 24*4096*256*2B
  _Float16* w1h = (_Float16*)(ws);
  _Float16* w2h = (_Float16*)(ws + 65536);
  _Float16* qp  = (_Float16*)(ws + 196608);
  _Float16* kp  = (_Float16*)(ws + 196608 + SZ);
  _Float16* kpT = (_Float16*)(ws + 196608 + 2 * SZ);  // reused as Wf after s_kernel
  _Float16* S   = (_Float16*)(ws + 196608 + 3 * SZ);  // reused in-place as Wr
  _Float16* vT  = (_Float16*)(ws + 196608 + 4 * SZ);  // 24MB
  _Float16* Wf  = kpT;
  _Float16* Wr  = S;

  prep_kernel<<<dim3(256), dim3(256), 0, stream>>>(w1, w2, w1h, w2h);
  vt_kernel<<<dim3(BH * NC), dim3(256), 0, stream>>>(v, vT);
  phi_kernel<<<dim3(2 * NROWS / 64), dim3(512), 0, stream>>>(q, k, b1, b2, w1h, w2h, qp, kp, kpT);
  s_kernel<<<dim3(BH * NC), dim3(512), 0, stream>>>(vT, kpT, S);
  prefix_kernel<<<dim3(BH * DD * FF / 256), dim3(256), 0, stream>>>(S, Wf);
  scan_kernel<<<dim3(BH * NC), dim3(512), 0, stream>>>(qp, kp, vT, Wf, Wr, out);
}

// Round 3
// 431.998 us; speedup vs baseline: 1.1067x; 1.1067x over previous
//
#include <hip/hip_runtime.h>

// TTRFluxLayer R6: phi v4 — 2 blocks/CU without spilling.
// k1 phi v4: 512 thr / 128-row tile / LDS 69.6KB union (xs|hs|os|ot) -> 2 blocks/CU.
//            launch_bounds(512,4) = 128 VGPR cap (R5's (512,8)=64 cap caused scratch
//            spill: +98MB WRITE, VGPR=32, MfmaUtil 7.9%). Weights read per-wave from
//            global/L2 (single-buffered bv[4] to keep peak regs ~96). x and h staged
//            in LDS (conversion + cross-wave reuse). kpT transpose tile XOR-swizzled
//            (R4/R5 ot scatter was 16-way bank conflict).
// k0 prep / k0b vt / k2 s / k3 pfx / k4 scan: unchanged.
// ws: w1h 64K | w2h 128K | qp 48M | kp 48M | kpT/Wf 48M | S/Wr 48M | vT 24M

typedef __attribute__((ext_vector_type(8))) _Float16 f16x8;
typedef __attribute__((ext_vector_type(4))) _Float16 f16x4;
typedef __attribute__((ext_vector_type(4))) float f32x4;

#define MFMA16(a, b, c) __builtin_amdgcn_mfma_f32_16x16x32_f16((a), (b), (c), 0, 0, 0)

constexpr int BH   = 24;
constexpr int NSEQ = 4096;
constexpr int DD   = 128;
constexpr int FF   = 256;
constexpr int CHK  = 128;
constexpr int NC   = NSEQ / CHK;     // 32
constexpr int NROWS = BH * NSEQ;     // 98304

// ---------------- k0: weight convert ----------------
__global__ void prep_kernel(const float* __restrict__ w1, const float* __restrict__ w2,
                            _Float16* __restrict__ w1h, _Float16* __restrict__ w2h) {
  int i = blockIdx.x * 256 + threadIdx.x;
  if (i < FF * DD) w1h[i] = (_Float16)w1[i];
  if (i < FF * FF) w2h[i] = (_Float16)w2[i];
}

// ---------------- k0b: v -> vT fp16 [bh][d][s] ----------------
__global__ void vt_kernel(const float* __restrict__ v, _Float16* __restrict__ vT) {
  __shared__ __align__(16) _Float16 lt[128][136];
  int blk = blockIdx.x;
  int c = blk & 31, bh = blk >> 5;
  const float* vc = v + ((size_t)bh * NSEQ + c * CHK) * DD;
  int tid = threadIdx.x;
#pragma unroll
  for (int it = 0; it < 16; ++it) {
    int flat = it * 1024 + tid * 4;  // 128s x 128d
    int s = flat >> 7, d0 = flat & 127;
    float4 xv = *(const float4*)&vc[(size_t)s * DD + d0];
    lt[d0 + 0][s] = (_Float16)xv.x;
    lt[d0 + 1][s] = (_Float16)xv.y;
    lt[d0 + 2][s] = (_Float16)xv.z;
    lt[d0 + 3][s] = (_Float16)xv.w;
  }
  __syncthreads();
#pragma unroll
  for (int it = 0; it < 8; ++it) {
    int flat = it * 256 + tid;  // 128d x 16 s-groups
    int d = flat >> 4, sg = flat & 15;
    *(f16x8*)&vT[((size_t)bh * DD + d) * NSEQ + c * CHK + sg * 8] =
        *(const f16x8*)&lt[d][sg * 8];
  }
}

// ---------------- k1: phi v4 (128-row tile, 512 thr, 2 blocks/CU) ----------------
__global__ __launch_bounds__(512, 4)
void phi_kernel(const float* __restrict__ q, const float* __restrict__ k,
                const float* __restrict__ b1, const float* __restrict__ b2,
                const _Float16* __restrict__ w1h, const _Float16* __restrict__ w2h,
                _Float16* __restrict__ qp, _Float16* __restrict__ kp,
                _Float16* __restrict__ kpT) {
  __shared__ __align__(16) char smem[69632];
  _Float16 (*xs)[136] = (_Float16(*)[136])smem;   // [128][136] phase1 (34.8KB)
  _Float16 (*hs)[264] = (_Float16(*)[264])smem;   // [128][264] phase2 (67.6KB)
  _Float16 (*os)[264] = (_Float16(*)[264])smem;   // [128][264] epilogue (alias)
  _Float16 (*ot)[136] = (_Float16(*)[136])smem;   // [256][136] epilogue-T (69.6KB)
  int blk = blockIdx.x;
  bool isk = (blk & 1);
  int rb = (blk >> 1) * 128;
  const float* src = isk ? k : q;
  _Float16* dst = isk ? kp : qp;
  int tid = threadIdx.x;
  int lane = tid & 63, wv = tid >> 6, lr = lane & 15, lq = lane >> 4;
  int wm = wv & 1, wn = wv >> 1;  // 2 row-strips(64) x 4 F-strips(64)

  // stage x (128x128 f32->f16)
#pragma unroll
  for (int it = 0; it < 8; ++it) {
    int flat = it * 512 + tid;  // 128 rows x 32 d-groups
    int r = flat >> 5, dg = flat & 31;
    float4 xv = *(const float4*)&src[(size_t)(rb + r) * DD + dg * 4];
    f16x4 hv = {(_Float16)xv.x, (_Float16)xv.y, (_Float16)xv.z, (_Float16)xv.w};
    *(f16x4*)&xs[r][dg * 4] = hv;
  }
  __syncthreads();

  // GEMM1: wave tile 64x64 over K=128; B-frags from global (L2), single-buffered
  f32x4 acc[4][4] = {};
#pragma unroll
  for (int ks = 0; ks < 4; ++ks) {
    f16x8 bv[4];
#pragma unroll
    for (int fn = 0; fn < 4; ++fn)
      bv[fn] = *(const f16x8*)&w1h[(size_t)(wn * 64 + fn * 16 + lr) * DD + ks * 32 + lq * 8];
    f16x8 av[4];
#pragma unroll
    for (int im = 0; im < 4; ++im)
      av[im] = *(const f16x8*)&xs[wm * 64 + im * 16 + lr][ks * 32 + lq * 8];
#pragma unroll
    for (int fn = 0; fn < 4; ++fn)
#pragma unroll
      for (int im = 0; im < 4; ++im) acc[im][fn] = MFMA16(av[im], bv[fn], acc[im][fn]);
  }
  __syncthreads();  // xs dead

  // hs = silu(acc + b1)
#pragma unroll
  for (int im = 0; im < 4; ++im)
#pragma unroll
    for (int fn = 0; fn < 4; ++fn) {
      int f = wn * 64 + fn * 16 + lr;
      float bb = b1[f];
      int r0 = wm * 64 + im * 16 + lq * 4;
#pragma unroll
      for (int r = 0; r < 4; ++r) {
        float xv = acc[im][fn][r] + bb;
        hs[r0 + r][f] = (_Float16)(xv * __builtin_amdgcn_rcpf(1.0f + __expf(-xv)));
      }
    }
  __syncthreads();

  // GEMM2: K=256; B-frags from global (L2), single-buffered
  f32x4 ac2[4][4] = {};
#pragma unroll
  for (int ks = 0; ks < 8; ++ks) {
    f16x8 bv[4];
#pragma unroll
    for (int fn = 0; fn < 4; ++fn)
      bv[fn] = *(const f16x8*)&w2h[(size_t)(wn * 64 + fn * 16 + lr) * FF + ks * 32 + lq * 8];
    f16x8 av[4];
#pragma unroll
    for (int im = 0; im < 4; ++im)
      av[im] = *(const f16x8*)&hs[wm * 64 + im * 16 + lr][ks * 32 + lq * 8];
#pragma unroll
    for (int fn = 0; fn < 4; ++fn)
#pragma unroll
      for (int im = 0; im < 4; ++im) ac2[im][fn] = MFMA16(av[im], bv[fn], ac2[im][fn]);
  }
  __syncthreads();  // hs dead

  // epilogue pass 1: row-major tile -> coalesced qp/kp stores
  int bh = rb >> 12, s0 = rb & 4095;
#pragma unroll
  for (int im = 0; im < 4; ++im)
#pragma unroll
    for (int fn = 0; fn < 4; ++fn) {
      int g = wn * 64 + fn * 16 + lr;
      float bb = b2[g];
      int r0 = wm * 64 + im * 16 + lq * 4;
#pragma unroll
      for (int r = 0; r < 4; ++r)
        os[r0 + r][g] = (_Float16)(ac2[im][fn][r] + bb);
    }
  __syncthreads();
#pragma unroll
  for (int it = 0; it < 8; ++it) {
    int flat = it * 512 + tid;  // 128 rows x 32 col-groups
    int r = flat >> 5, cg = flat & 31;
    *(f16x8*)&dst[(size_t)(rb + r) * FF + cg * 8] = *(const f16x8*)&os[r][cg * 8];
  }

  // epilogue pass 2 (k only): XOR-swizzled transpose tile -> coalesced kpT stores
  if (isk) {
    __syncthreads();  // os drained
#pragma unroll
    for (int im = 0; im < 4; ++im)
#pragma unroll
      for (int fn = 0; fn < 4; ++fn) {
        int g = wn * 64 + fn * 16 + lr;
        float bb = b2[g];
        int r0 = wm * 64 + im * 16 + lq * 4;
        int swz = (g & 7) << 3;
#pragma unroll
        for (int r = 0; r < 4; ++r)
          ot[g][(r0 + r) ^ swz] = (_Float16)(ac2[im][fn][r] + bb);
      }
    __syncthreads();
#pragma unroll
    for (int it = 0; it < 8; ++it) {
      int flat = it * 512 + tid;  // 256 f x 16 s-groups
      int f = flat >> 4, sg = flat & 15;
      *(f16x8*)&kpT[((size_t)bh * FF + f) * NSEQ + s0 + sg * 8] =
          *(const f16x8*)&ot[f][(sg * 8) ^ ((f & 7) << 3)];
    }
  }
}

// ---------------- k2: S^T[d][f] per chunk ----------------
__global__ __launch_bounds__(512, 2)
void s_kernel(const _Float16* __restrict__ vT, const _Float16* __restrict__ kpT,
              _Float16* __restrict__ S) {
  __shared__ __align__(16) _Float16 vt[128][136];
  __shared__ __align__(16) _Float16 kt[256][136];
  int blk = blockIdx.x;
  int c = blk & 31, bh = blk >> 5;
  int tid = threadIdx.x;
#pragma unroll
  for (int it = 0; it < 4; ++it) {
    int flat = it * 512 + tid;
    int d = flat >> 4, sg = flat & 15;
    *(f16x8*)&vt[d][sg * 8] = *(const f16x8*)&vT[((size_t)bh * DD + d) * NSEQ + c * CHK + sg * 8];
  }
#pragma unroll
  for (int it = 0; it < 8; ++it) {
    int flat = it * 512 + tid;
    int f = flat >> 4, sg = flat & 15;
    *(f16x8*)&kt[f][sg * 8] = *(const f16x8*)&kpT[((size_t)bh * FF + f) * NSEQ + c * CHK + sg * 8];
  }
  __syncthreads();
  int lane = tid & 63, wv = tid >> 6, lr = lane & 15, lq = lane >> 4;
  int wmd = wv & 1, wnf = wv >> 1;
  f32x4 acc[4][4] = {};
#pragma unroll
  for (int ks = 0; ks < 4; ++ks) {
    f16x8 av[4];
#pragma unroll
    for (int im = 0; im < 4; ++im)
      av[im] = *(const f16x8*)&vt[wmd * 64 + im * 16 + lr][ks * 32 + lq * 8];
#pragma unroll
    for (int fn = 0; fn < 4; ++fn) {
      f16x8 bv = *(const f16x8*)&kt[wnf * 64 + fn * 16 + lr][ks * 32 + lq * 8];
#pragma unroll
      for (int im = 0; im < 4; ++im) acc[im][fn] = MFMA16(av[im], bv, acc[im][fn]);
    }
  }
  _Float16* Sp = S + ((size_t)bh * NC + c) * (size_t)(DD * FF);
#pragma unroll
  for (int im = 0; im < 4; ++im)
#pragma unroll
    for (int fn = 0; fn < 4; ++fn) {
      int f = wnf * 64 + fn * 16 + lr;
#pragma unroll
      for (int r = 0; r < 4; ++r) {
        int d = wmd * 64 + im * 16 + lq * 4 + r;
        Sp[(size_t)d * FF + f] = (_Float16)acc[im][fn][r];
      }
    }
}

// ---------------- k3: prefix->Wf, suffix in-place over S (becomes Wr) ------
__global__ void prefix_kernel(_Float16* S_Wr, _Float16* __restrict__ Wf) {
  size_t idx = (size_t)blockIdx.x * 256 + threadIdx.x;
  int bh = (int)(idx >> 15);
  int df = (int)(idx & 32767);
  size_t base = (size_t)bh * NC * 32768 + df;
  float vals[NC];
#pragma unroll
  for (int c = 0; c < NC; ++c) vals[c] = (float)S_Wr[base + (size_t)c * 32768];
  float run = 0.f;
#pragma unroll
  for (int c = 0; c < NC; ++c) { Wf[base + (size_t)c * 32768] = (_Float16)run; run += vals[c]; }
  run = 0.f;
#pragma unroll
  for (int c = NC - 1; c >= 0; --c) { S_Wr[base + (size_t)c * 32768] = (_Float16)run; run += vals[c]; }
}

// ---------------- k4: fused phase-2 scan (full chunk per block) ----------------
__global__ __launch_bounds__(512, 2)
void scan_kernel(const _Float16* __restrict__ qp, const _Float16* __restrict__ kp,
                 const _Float16* __restrict__ vT, const _Float16* __restrict__ Wf,
                 const _Float16* __restrict__ Wr, float* __restrict__ out) {
  __shared__ __align__(16) _Float16 vt[128][136];
  __shared__ __align__(16) _Float16 P[128][136];
  int blk = blockIdx.x;
  int c = blk & 31, bh = blk >> 5;
  const _Float16* qpc = qp + ((size_t)bh * NSEQ + c * CHK) * FF;
  const _Float16* kpc = kp + ((size_t)bh * NSEQ + c * CHK) * FF;
  int tid = threadIdx.x, lane = tid & 63, wv = tid >> 6, lr = lane & 15, lq = lane >> 4;
  int wm = wv & 3, wn = wv >> 2;  // wm: 4x32 rows; wn: 2x64 (s-half in A, d-half in B)

  // aq: 16 frags (reused by phase A and inter), batched but bounded
  f16x8 aq[2][8];
#pragma unroll
  for (int im = 0; im < 2; ++im)
#pragma unroll
    for (int ks = 0; ks < 8; ++ks)
      aq[im][ks] = *(const f16x8*)&qpc[(size_t)(wm * 32 + im * 16 + lr) * FF + ks * 32 + lq * 8];
  // stage vt (b128, conflict-free)
#pragma unroll
  for (int it = 0; it < 4; ++it) {
    int flat = it * 512 + tid;
    int d = flat >> 4, sg = flat & 15;
    *(f16x8*)&vt[d][sg * 8] = *(const f16x8*)&vT[((size_t)bh * DD + d) * NSEQ + c * CHK + sg * 8];
  }
  // Phase A: P = qp.kp^T with bk double-buffer over j
  f16x8 bk[2][8];
#pragma unroll
  for (int ks = 0; ks < 8; ++ks)
    bk[0][ks] = *(const f16x8*)&kpc[(size_t)(wn * 64 + lr) * FF + ks * 32 + lq * 8];
  f32x4 pacc[2][4] = {};
#pragma unroll
  for (int j = 0; j < 4; ++j) {
    int cur = j & 1;
    if (j < 3)
#pragma unroll
      for (int ks = 0; ks < 8; ++ks)
        bk[cur ^ 1][ks] = *(const f16x8*)&kpc[(size_t)(wn * 64 + (j + 1) * 16 + lr) * FF + ks * 32 + lq * 8];
#pragma unroll
    for (int ks = 0; ks < 8; ++ks)
#pragma unroll
      for (int im = 0; im < 2; ++im)
        pacc[im][j] = MFMA16(aq[im][ks], bk[cur][ks], pacc[im][j]);
  }
#pragma unroll
  for (int im = 0; im < 2; ++im)
#pragma unroll
    for (int j = 0; j < 4; ++j)
#pragma unroll
      for (int r = 0; r < 4; ++r)
        P[wm * 32 + im * 16 + lq * 4 + r][wn * 64 + j * 16 + lr] = (_Float16)pacc[im][j][r];

  // prefetch W frags for jd=0 (before barrier: overlaps P writes)
  const _Float16* Wfc = Wf + ((size_t)bh * NC + c) * (size_t)(DD * FF);
  const _Float16* Wrc = Wr + ((size_t)bh * NC + c) * (size_t)(DD * FF);
  f16x8 bf[8], br[8];
#pragma unroll
  for (int ks = 0; ks < 8; ++ks) {
    int d = wn * 64 + lr;
    bf[ks] = *(const f16x8*)&Wfc[(size_t)d * FF + ks * 32 + lq * 8];
    br[ks] = *(const f16x8*)&Wrc[(size_t)d * FF + ks * 32 + lq * 8];
  }
  __syncthreads();

  // Phase B: inter (q.W) per d-group; W prefetch 1 group ahead; intra interleaved
  f32x4 af[2][4] = {}, ar[2][4] = {};
#pragma unroll
  for (int jd = 0; jd < 4; ++jd) {
#pragma unroll
    for (int ks = 0; ks < 8; ++ks)
#pragma unroll
      for (int im = 0; im < 2; ++im) {
        af[im][jd] = MFMA16(aq[im][ks], bf[ks], af[im][jd]);
        ar[im][jd] = MFMA16(aq[im][ks], br[ks], ar[im][jd]);
      }
    if (jd < 3)
#pragma unroll
      for (int ks = 0; ks < 8; ++ks) {
        int d = wn * 64 + (jd + 1) * 16 + lr;
        bf[ks] = *(const f16x8*)&Wfc[(size_t)d * FF + ks * 32 + lq * 8];
        br[ks] = *(const f16x8*)&Wrc[(size_t)d * FF + ks * 32 + lq * 8];
      }
    // intra k-step ks=jd (LDS-only; covers W prefetch latency)
    {
      int ks = jd;
      f16x8 bv[4];
#pragma unroll
      for (int jd2 = 0; jd2 < 4; ++jd2)
        bv[jd2] = *(const f16x8*)&vt[wn * 64 + jd2 * 16 + lr][ks * 32 + lq * 8];
#pragma unroll
      for (int im = 0; im < 2; ++im) {
        int irow = wm * 32 + im * 16 + lr;
        f16x8 p = *(const f16x8*)&P[irow][ks * 32 + lq * 8];
        f16x8 pf = p, pr = p;
#pragma unroll
        for (int jj = 0; jj < 8; ++jj) {
          int s = ks * 32 + lq * 8 + jj;
          pf[jj] = (s <= irow) ? p[jj] : (_Float16)0.0f;
          pr[jj] = (s >= irow) ? p[jj] : (_Float16)0.0f;
        }
#pragma unroll
        for (int jd2 = 0; jd2 < 4; ++jd2) {
          af[im][jd2] = MFMA16(pf, bv[jd2], af[im][jd2]);
          ar[im][jd2] = MFMA16(pr, bv[jd2], ar[im][jd2]);
        }
      }
    }
  }

  // epilogue
  float* oc = out + ((size_t)bh * NSEQ + c * CHK) * DD;
#pragma unroll
  for (int im = 0; im < 2; ++im)
#pragma unroll
    for (int jd = 0; jd < 4; ++jd) {
      int d = wn * 64 + jd * 16 + lr;
#pragma unroll
      for (int r = 0; r < 4; ++r) {
        int il = wm * 32 + im * 16 + lq * 4 + r;
        int gi = c * CHK + il;
        oc[(size_t)il * DD + d] = af[im][jd][r] / (float)(gi + 1) + ar[im][jd][r] / (float)(NSEQ - gi);
      }
    }
}

// ---------------- launcher ----------------
extern "C" void kernel_launch(void* const* d_in, const int* in_sizes, int n_in,
                              void* d_out, int out_size, void* d_ws, size_t ws_size,
                              hipStream_t stream) {
  const float* q  = (const float*)d_in[0];
  const float* k  = (const float*)d_in[1];
  const float* v  = (const float*)d_in[2];
  const float* w1 = (const float*)d_in[3];
  const float* b1 = (const float*)d_in[4];
  const float* w2 = (const float*)d_in[5];
  const float* b2 = (const float*)d_in[6];
  float* out = (float*)d_out;

  char* ws = (char*)d_ws;
  const size_t SZ = 50331648ull;  // 24*4096*256*2B
  _Float16* w1h = (_Float16*)(ws);
  _Float16* w2h = (_Float16*)(ws + 65536);
  _Float16* qp  = (_Float16*)(ws + 196608);
  _Float16* kp  = (_Float16*)(ws + 196608 + SZ);
  _Float16* kpT = (_Float16*)(ws + 196608 + 2 * SZ);  // reused as Wf after s_kernel
  _Float16* S   = (_Float16*)(ws + 196608 + 3 * SZ);  // reused in-place as Wr
  _Float16* vT  = (_Float16*)(ws + 196608 + 4 * SZ);  // 24MB
  _Float16* Wf  = kpT;
  _Float16* Wr  = S;

  prep_kernel<<<dim3(256), dim3(256), 0, stream>>>(w1, w2, w1h, w2h);
  vt_kernel<<<dim3(BH * NC), dim3(256), 0, stream>>>(v, vT);
  phi_kernel<<<dim3(2 * NROWS / 128), dim3(512), 0, stream>>>(q, k, b1, b2, w1h, w2h, qp, kp, kpT);
  s_kernel<<<dim3(BH * NC), dim3(512), 0, stream>>>(vT, kpT, S);
  prefix_kernel<<<dim3(BH * DD * FF / 256), dim3(256), 0, stream>>>(S, Wf);
  scan_kernel<<<dim3(BH * NC), dim3(512), 0, stream>>>(qp, kp, vT, Wf, Wr, out);
}